// Round 10
// baseline (1277.607 us; speedup 1.0000x reference)
//
#include <hip/hip_runtime.h>

typedef short bf16x8 __attribute__((ext_vector_type(8)));
typedef float f32x4 __attribute__((ext_vector_type(4)));

#define BN_EPS 1e-5f
#define ELL_CAP 48

__device__ __forceinline__ unsigned short f2b(float x) {
    union { float f; unsigned u; } v; v.f = x;
    unsigned r = v.u + 0x7FFFu + ((v.u >> 16) & 1u);
    return (unsigned short)(r >> 16);
}
__device__ __forceinline__ float b2f(unsigned short h) {
    union { unsigned u; float f; } v; v.u = ((unsigned)h) << 16;
    return v.f;
}
__device__ __forceinline__ void atomAddF(float* p, float v) { unsafeAtomicAdd(p, v); }

__device__ __forceinline__ void gload16(const void* g, void* l) {
    __builtin_amdgcn_global_load_lds((const __attribute__((address_space(1))) void*)g,
                                     (__attribute__((address_space(3))) void*)l, 16, 0, 0);
}

// ---- fused prep: all 6 weight transposes (K-blocked WT2 layout), all 4
//      concat-casts, all 5 ELL builds — one dispatch, fixed geometry.
//      Block ranges (256 thr): [0,6932) transposes, [6932,14432) casts,
//      [14432,18188) ell. All tasks independent (read inputs only). ----
__global__ __launch_bounds__(256)
void prep_all(const float* __restrict__ W_up2, const float* __restrict__ W_up1,
              const float* __restrict__ W_up0, const float* __restrict__ W_s0,
              const float* __restrict__ W_s1,  const float* __restrict__ W_s2,
              const float* __restrict__ f0, const float* __restrict__ f1,
              const float* __restrict__ f2, const float* __restrict__ f3,
              const int* __restrict__ up2_out, const int* __restrict__ up1_out,
              const int* __restrict__ up0_out, const int* __restrict__ sm0_out,
              const int* __restrict__ sm1_out,
              unsigned short* __restrict__ WT, unsigned short* __restrict__ xb3,
              unsigned short* __restrict__ xc2, unsigned short* __restrict__ xc1,
              unsigned short* __restrict__ xc0,
              int* __restrict__ cnt_all, int* __restrict__ ell_all) {
    int b = blockIdx.x, tid = threadIdx.x;
    if (b < 6932) {
        // ---- weight transposes: W[k][ci][co] f32 -> bf16 chunk
        //      ((k*KB + ci/32)*4 + (ci%32)/8)*CoutPad + co  (8 ci values/chunk)
        const float* W; unsigned short* dst; int Cin, Cout, CinPad, CoutPad, base;
        if (b < 216)       { W = W_up2; dst = WT;                      Cin = 128; Cout = 128; CinPad = 128; CoutPad = 128; base = 0; }
        else if (b < 864)  { W = W_up1; dst = WT + (size_t)55296 * 8;  Cin = 192; Cout = 192; CinPad = 192; CoutPad = 256; base = 216; }
        else if (b < 1620) { W = W_up0; dst = WT + (size_t)221184 * 8; Cin = 224; Cout = 224; CinPad = 224; CoutPad = 256; base = 864; }
        else if (b < 3348) { W = W_s0;  dst = WT + (size_t)414720 * 8; Cin = 240; Cout = 512; CinPad = 256; CoutPad = 512; base = 1620; }
        else if (b < 6804) { W = W_s1;  dst = WT + (size_t)857088 * 8; Cin = 512; Cout = 512; CinPad = 512; CoutPad = 512; base = 3348; }
        else               { W = W_s2;  dst = WT + (size_t)1741824 * 8; Cin = 512; Cout = 512; CinPad = 512; CoutPad = 512; base = 6804; }
        int i = (b - base) * 256 + tid;
        int CB = CinPad >> 3;
        int per_k = CB * CoutPad;
        int k = i / per_k, r = i - k * per_k;
        int cb = r / CoutPad, co = r - cb * CoutPad;
        const float* Wk = W + (size_t)k * Cin * Cout;
        bf16x8 ov;
        #pragma unroll
        for (int j = 0; j < 8; j++) {
            int ci = cb * 8 + j;
            float v = (ci < Cin && co < Cout) ? Wk[(size_t)ci * Cout + co] : 0.f;
            ov[j] = (short)f2b(v);
        }
        *(bf16x8*)(dst + (size_t)i * 8) = ov;
    } else if (b < 14432) {
        // ---- concat casts: fp32 [N,Csrc] -> bf16 dst[n*stride+off+j], zero-pad
        int bb = b - 6932;
        const float* src; unsigned short* dst; int N, Csrc, stride, off, wid, base;
        if (bb < 1000)      { src = f3; dst = xb3; N = 2000;  Csrc = 128; stride = 128; off = 0;   wid = 128; base = 0; }
        else if (bb < 2250) { src = f2; dst = xc2; N = 5000;  Csrc = 64;  stride = 192; off = 128; wid = 64;  base = 1000; }
        else if (bb < 3750) { src = f1; dst = xc1; N = 12000; Csrc = 32;  stride = 224; off = 192; wid = 32;  base = 2250; }
        else                { src = f0; dst = xc0; N = 30000; Csrc = 16;  stride = 256; off = 224; wid = 32;  base = 3750; }
        int i = (bb - base) * 256 + tid;
        if (i < N * wid) {
            int n = i / wid, j = i % wid;
            float v = (j < Csrc) ? src[(size_t)n * Csrc + j] : 0.f;
            dst[(size_t)n * stride + off + j] = f2b(v);
        }
    } else {
        // ---- ELL builds: entry e = k*M+m scattered to out row o
        int bb = b - 14432;
        const int* oidx; int total, cb_, base;
        if (bb < 169)       { oidx = up2_out; total = 43200;  cb_ = 0;     base = 0; }
        else if (bb < 591)  { oidx = up1_out; total = 108000; cb_ = 5000;  base = 169; }
        else if (bb < 1646) { oidx = up0_out; total = 270000; cb_ = 17000; base = 591; }
        else if (bb < 2701) { oidx = sm0_out; total = 270000; cb_ = 47000; base = 1646; }
        else                { oidx = sm1_out; total = 270000; cb_ = 77000; base = 2701; }
        int e = (bb - base) * 256 + tid;
        if (e < total) {
            int o = oidx[e];
            int pos = atomicAdd(&cnt_all[cb_ + o], 1);
            if (pos < ELL_CAP) ell_all[((size_t)cb_ + o) * ELL_CAP + pos] = e;
        }
    }
}

// ---- BN stats over bf16 activations ----
__global__ void bn_stats_bf16(const unsigned short* __restrict__ x, float* __restrict__ stats,
                              int N, int C, int rowsPerBlock) {
    int r0 = blockIdx.x * rowsPerBlock;
    int r1 = min(N, r0 + rowsPerBlock);
    for (int c = threadIdx.x; c < C; c += blockDim.x) {
        float s = 0.f, s2 = 0.f;
        for (int r = r0; r < r1; r++) {
            float v = b2f(x[(size_t)r * C + c]);
            s += v; s2 += v * v;
        }
        atomAddF(&stats[c], s);
        atomAddF(&stats[C + c], s2);
    }
}

// ---- BN stats over fp32 (dense s2 output) ----
__global__ void bn_stats(const float* __restrict__ x, float* __restrict__ stats,
                         int N, int C, int rowsPerBlock) {
    int r0 = blockIdx.x * rowsPerBlock;
    int r1 = min(N, r0 + rowsPerBlock);
    for (int c = threadIdx.x; c < C; c += blockDim.x) {
        float s = 0.f, s2 = 0.f;
        for (int r = r0; r < r1; r++) {
            float v = x[(size_t)r * C + c];
            s += v; s2 += v * v;
        }
        atomAddF(&stats[c], s);
        atomAddF(&stats[C + c], s2);
    }
}

// ---- BN apply + ReLU: bf16 src [N,C] -> bf16 dst (strided, for concat), x8 ----
__global__ void bn_apply_bb(const unsigned short* __restrict__ x, const float* __restrict__ stats,
                            const float* __restrict__ g, const float* __restrict__ b,
                            unsigned short* __restrict__ dst, int N, int C, int stride, float invN) {
    int i = blockIdx.x * blockDim.x + threadIdx.x;
    int C8 = C >> 3;
    if (i >= N * C8) return;
    int n = i / C8, cb = (i - n * C8) << 3;
    bf16x8 xv = *(const bf16x8*)(x + (size_t)n * C + cb);
    bf16x8 ov;
    #pragma unroll
    for (int j = 0; j < 8; j++) {
        int cc = cb + j;
        float mean = stats[cc] * invN;
        float var = stats[C + cc] * invN - mean * mean;
        float scale = g[cc] * rsqrtf(var + BN_EPS);
        float shift = b[cc] - mean * scale;
        ov[j] = (short)f2b(fmaxf(0.f, b2f((unsigned short)xv[j]) * scale + shift));
    }
    *(bf16x8*)(dst + (size_t)n * stride + cb) = ov;
}

// ---- BN apply + ReLU in-place fp32 (final output), x4 ----
__global__ void bn_apply_f32(float* __restrict__ x, const float* __restrict__ stats,
                             const float* __restrict__ g, const float* __restrict__ b,
                             int N, int C, float invN) {
    int i = blockIdx.x * blockDim.x + threadIdx.x;
    int C4 = C >> 2;
    if (i >= N * C4) return;
    int n = i / C4, cb = (i - n * C4) << 2;
    float* p = x + (size_t)n * C + cb;
    float4 xv = *(const float4*)p;
    float vs[4] = {xv.x, xv.y, xv.z, xv.w};
    #pragma unroll
    for (int j = 0; j < 4; j++) {
        int cc = cb + j;
        float mean = stats[cc] * invN;
        float var = stats[C + cc] * invN - mean * mean;
        float scale = g[cc] * rsqrtf(var + BN_EPS);
        float shift = b[cc] - mean * scale;
        vs[j] = fmaxf(0.f, vs[j] * scale + shift);
    }
    float4 ov = {vs[0], vs[1], vs[2], vs[3]};
    *(float4*)p = ov;
}

// ---- Phase B: sum bf16 partial rows per output row (CW-col chunk), write bf16.
//      Pre-scan skips untouched rows on accum passes (active when CK<27);
//      4-deep independent partial-row loads in flight. ----
template<int CW>
__global__ __launch_bounds__(256)
void reduce_ell(const unsigned short* __restrict__ c, const int* __restrict__ cnt,
                const int* __restrict__ ell, unsigned short* __restrict__ outb,
                int nb, int Cout, int Nout, int k0row, int k1row, int accum) {
    constexpr int LPR = CW / 8;        // lanes per row
    constexpr int RPB = 256 / LPR;     // rows per block
    int tid = threadIdx.x;
    int o = blockIdx.x * RPB + tid / LPR;
    if (o >= Nout) return;
    int colL = (tid % LPR) * 8;
    int n = min(cnt[o], ELL_CAP);
    const int* er = ell + (size_t)o * ELL_CAP;

    // cheap pre-scan: any entry in this k-chunk?
    int nin = 0;
    for (int i = 0; i < n; i++) {
        int e = er[i];
        nin += (e >= k0row && e < k1row) ? 1 : 0;
    }
    if (accum && nin == 0) return;     // untouched row: skip RMW entirely

    float a[8] = {0.f, 0.f, 0.f, 0.f, 0.f, 0.f, 0.f, 0.f};
    if (nin > 0) {
        int i = 0;
        for (; i + 3 < n; i += 4) {    // 4 independent partial-row loads in flight
            int e0 = er[i], e1 = er[i + 1], e2 = er[i + 2], e3 = er[i + 3];
            float m0 = (e0 >= k0row && e0 < k1row) ? 1.f : 0.f;
            float m1 = (e1 >= k0row && e1 < k1row) ? 1.f : 0.f;
            float m2 = (e2 >= k0row && e2 < k1row) ? 1.f : 0.f;
            float m3 = (e3 >= k0row && e3 < k1row) ? 1.f : 0.f;
            size_t r0 = (m0 != 0.f) ? (size_t)(e0 - k0row) : 0;
            size_t r1 = (m1 != 0.f) ? (size_t)(e1 - k0row) : 0;
            size_t r2 = (m2 != 0.f) ? (size_t)(e2 - k0row) : 0;
            size_t r3 = (m3 != 0.f) ? (size_t)(e3 - k0row) : 0;
            bf16x8 u0 = __builtin_nontemporal_load((const bf16x8*)(c + r0 * CW + colL));
            bf16x8 u1 = __builtin_nontemporal_load((const bf16x8*)(c + r1 * CW + colL));
            bf16x8 u2 = __builtin_nontemporal_load((const bf16x8*)(c + r2 * CW + colL));
            bf16x8 u3 = __builtin_nontemporal_load((const bf16x8*)(c + r3 * CW + colL));
            #pragma unroll
            for (int j = 0; j < 8; j++)
                a[j] += (m0 * b2f((unsigned short)u0[j]) + m1 * b2f((unsigned short)u1[j]))
                      + (m2 * b2f((unsigned short)u2[j]) + m3 * b2f((unsigned short)u3[j]));
        }
        for (; i < n; i++) {
            int e0 = er[i];
            float m0 = (e0 >= k0row && e0 < k1row) ? 1.f : 0.f;
            size_t r0 = (m0 != 0.f) ? (size_t)(e0 - k0row) : 0;
            bf16x8 u0 = __builtin_nontemporal_load((const bf16x8*)(c + r0 * CW + colL));
            #pragma unroll
            for (int j = 0; j < 8; j++) a[j] += m0 * b2f((unsigned short)u0[j]);
        }
    }
    int gc = nb + colL;
    if (gc < Cout) {   // Cout % 8 == 0 so whole 8-group is in-range
        unsigned short* op = outb + (size_t)o * Cout + gc;
        if (accum) {
            bf16x8 prev = *(const bf16x8*)op;
            #pragma unroll
            for (int j = 0; j < 8; j++) a[j] += b2f((unsigned short)prev[j]);
        }
        bf16x8 w;
        #pragma unroll
        for (int j = 0; j < 8; j++) w[j] = (short)f2b(a[j]);
        *(bf16x8*)op = w;
    }
}

// ---- Phase A: per-k gather GEMM, 128xTN tile, BK=32, fully async staging.
//      (R8/R9 config — best-total; byte-identical compute.)
//      A: direct global_load_lds gather, source-chunk XOR pre-swizzle (m173),
//         linear [128][32] LDS dest, read slot = seg ^ (laneM&3).
//      B: K-blocked WT2, lane-contiguous global_load_lds.
//      Both prefetch distance 2, 3 slots, uniform counted vmcnt + raw s_barrier.
//      LDS 72KB x 2 blocks/CU; register-limited at TN=256 (R4: 3 blocks spills). ----
template<int TN, bool DENSE>
__global__ __launch_bounds__(256, 2)
void spconv_gemm(const unsigned short* __restrict__ A, const unsigned short* __restrict__ BT,
                 const int* __restrict__ in_idx, unsigned short* __restrict__ cpart,
                 float* __restrict__ outf, int M, int Kp, int CoutPad, int nbase, int kbase) {
    constexpr int WN = TN / 32;        // B frags per wave
    constexpr int NBQ = (TN * 4) / 256; // B staging instrs per thread per k-step
    constexpr int BUFA = 128 * 32;     // shorts per A slot (8KB), linear [128][32]
    constexpr int BUFB = TN * 32;      // shorts per B slot
    constexpr int VW = NBQ + 2;        // steady top-of-loop vmcnt (batch t+1 in flight)
    __shared__ __align__(16) unsigned short As[3 * BUFA];
    __shared__ __align__(16) unsigned short Bs[3 * BUFB];
    int tid = threadIdx.x, wave = tid >> 6, lane = tid & 63;
    int wr = wave >> 1, wc = wave & 1;
    int m0 = blockIdx.x * 128;
    int n0 = nbase + blockIdx.y * TN;
    int kzl = blockIdx.z, kz = kbase + kzl;

    // A gather: lane covers (row_local rl, dest slot) ; source chunk = slot ^ (rl&3)
    int rl = lane >> 2, slot = lane & 3;
    int chunk = slot ^ (rl & 3);
    int ra0 = wave * 32 + rl, ra1 = ra0 + 16;   // (ra&3) == (rl&3)
    size_t arow0, arow1;
    if constexpr (DENSE) {
        arow0 = (size_t)min(m0 + ra0, M - 1);
        arow1 = (size_t)min(m0 + ra1, M - 1);
    } else {
        const int* idxk = in_idx + (size_t)kz * M;
        arow0 = (m0 + ra0 < M) ? (size_t)idxk[m0 + ra0] : 0;
        arow1 = (m0 + ra1 < M) ? (size_t)idxk[m0 + ra1] : 0;
    }
    const unsigned short* gA0 = A + arow0 * Kp + chunk * 8;
    const unsigned short* gA1 = A + arow1 * Kp + chunk * 8;
    // wave-uniform LDS dests (lane offset is implicit lane*16B):
    unsigned short* lA0 = As + (size_t)(wave * 32) * 32;        // rows wave*32..+15
    unsigned short* lA1 = As + (size_t)(wave * 32 + 16) * 32;   // rows +16..+31

    // WT2: chunk ((k*KB + kb)*4 + seg)*CoutPad + co
    const unsigned short* BTk = BT + (size_t)kz * CoutPad * Kp;
    const unsigned short* gB[NBQ];
    unsigned short* lB[NBQ];
    #pragma unroll
    for (int q = 0; q < NBQ; q++) {
        int c0 = q * 256 + wave * 64;           // chunk id within the tile
        int seg0 = c0 / TN, col0 = c0 % TN;
        gB[q] = BTk + ((size_t)seg0 * CoutPad + (size_t)(n0 + col0 + lane)) * 8;
        lB[q] = Bs + (size_t)c0 * 8;            // slot-relative; add slot*BUFB
    }
    const size_t bstep = (size_t)CoutPad * 32;   // shorts per k-iter (kb+1)

    f32x4 acc[4][WN];
    #pragma unroll
    for (int i = 0; i < 4; i++)
        #pragma unroll
        for (int j = 0; j < WN; j++) acc[i][j] = (f32x4)(0.f);

    int laneM = lane & 15, seg = lane >> 4;
    // read: row (wr*64 + i*16 + laneM); chunk seg lives at slot seg^(row&3)=seg^(laneM&3)
    int aoff = (wr * 64 + laneM) * 32 + ((seg ^ (laneM & 3)) << 3);
    int boff = (seg * TN + wc * (TN / 2) + laneM) * 8;

    int nIter = Kp >> 5;

    // batch issue: A(2) + B(NBQ) gloads for k-step s into slot s%3
    auto stage = [&](int s) {
        int sa = (s % 3) * BUFA, sb = (s % 3) * BUFB;
        gload16(gA0 + s * 32, lA0 + sa);
        gload16(gA1 + s * 32, lA1 + sa);
        #pragma unroll
        for (int q = 0; q < NBQ; q++) gload16(gB[q] + (size_t)s * bstep, lB[q] + sb);
    };

    // prologue: batch(0), batch(1)
    stage(0);
    if (nIter > 1) stage(1); else stage(0);   // keep queue depth uniform

    for (int t = 0; t < nIter; t++) {
        // drain batch(t), leave batch(t+1)'s VW loads in flight across the barrier
        asm volatile("s_waitcnt vmcnt(%0)" :: "n"(VW) : "memory");
        __builtin_amdgcn_s_barrier();
        __builtin_amdgcn_sched_barrier(0);

        const unsigned short* ab = As + (t % 3) * BUFA + aoff;
        const unsigned short* bb = Bs + (t % 3) * BUFB + boff;
        bf16x8 af[4], bfr[WN];
        #pragma unroll
        for (int i = 0; i < 4; i++) af[i] = *(const bf16x8*)(ab + i * 512);
        #pragma unroll
        for (int j = 0; j < WN; j++) bfr[j] = *(const bf16x8*)(bb + j * 128);

        // batch(t+2), clamped to keep the VMEM queue depth constant; the dup
        // targets slot (t+2)%3 which is never the slot read this or next body.
        int tn = (t + 2 < nIter) ? (t + 2) : (nIter - 1);
        {
            int sa = ((t + 2) % 3) * BUFA, sb = ((t + 2) % 3) * BUFB;
            gload16(gA0 + tn * 32, lA0 + sa);
            gload16(gA1 + tn * 32, lA1 + sa);
            #pragma unroll
            for (int q = 0; q < NBQ; q++) gload16(gB[q] + (size_t)tn * bstep, lB[q] + sb);
        }

        #pragma unroll
        for (int i = 0; i < 4; i++)
            #pragma unroll
            for (int j = 0; j < WN; j++)
                acc[i][j] = __builtin_amdgcn_mfma_f32_16x16x32_bf16(af[i], bfr[j], acc[i][j], 0, 0, 0);
    }

    // C/D layout: col=lane&15, row=(lane>>4)*4+r  [m89/m91 verified]
    int rbase = seg * 4;
    #pragma unroll
    for (int i = 0; i < 4; i++) {
        #pragma unroll
        for (int r = 0; r < 4; r++) {
            int gm = m0 + wr * 64 + i * 16 + rbase + r;
            if (gm < M) {
                #pragma unroll
                for (int j = 0; j < WN; j++) {
                    int colL = wc * (TN / 2) + j * 16 + laneM;
                    if constexpr (DENSE) {
                        outf[(size_t)gm * CoutPad + n0 + colL] = acc[i][j][r];
                    } else {
                        __builtin_nontemporal_store(
                            (unsigned short)f2b(acc[i][j][r]),
                            &cpart[((size_t)kzl * M + gm) * TN + colL]);
                    }
                }
            }
        }
    }
}

static inline int div_up(int a, int b) { return (a + b - 1) / b; }

extern "C" void kernel_launch(void* const* d_in, const int* in_sizes, int n_in,
                              void* d_out, int out_size, void* d_ws, size_t ws_size,
                              hipStream_t stream) {
    const float* f0 = (const float*)d_in[0];
    const float* f1 = (const float*)d_in[1];
    const float* f2 = (const float*)d_in[2];
    const float* f3 = (const float*)d_in[3];
    const float* W_up2 = (const float*)d_in[4];
    const float* W_up1 = (const float*)d_in[5];
    const float* W_up0 = (const float*)d_in[6];
    const float* W_s0  = (const float*)d_in[7];
    const float* W_s1  = (const float*)d_in[8];
    const float* W_s2  = (const float*)d_in[9];
    const float* g_up2 = (const float*)d_in[10]; const float* b_up2 = (const float*)d_in[11];
    const float* g_up1 = (const float*)d_in[12]; const float* b_up1 = (const float*)d_in[13];
    const float* g_up0 = (const float*)d_in[14]; const float* b_up0 = (const float*)d_in[15];
    const float* g_s0  = (const float*)d_in[16]; const float* b_s0  = (const float*)d_in[17];
    const float* g_s1  = (const float*)d_in[18]; const float* b_s1  = (const float*)d_in[19];
    const float* g_s2  = (const float*)d_in[20]; const float* b_s2  = (const float*)d_in[21];
    const int* up2_in  = (const int*)d_in[22]; const int* up2_out = (const int*)d_in[23];
    const int* up1_in  = (const int*)d_in[24]; const int* up1_out = (const int*)d_in[25];
    const int* up0_in  = (const int*)d_in[26]; const int* up0_out = (const int*)d_in[27];
    const int* sm0_in  = (const int*)d_in[28]; const int* sm0_out = (const int*)d_in[29];
    const int* sm1_in  = (const int*)d_in[30]; const int* sm1_out = (const int*)d_in[31];

    char* ws = (char*)d_ws;
    auto alloc = [&](size_t bytes) { char* p = ws; ws += (bytes + 255) & ~(size_t)255; return p; };

    // per-layer weight regions (bf16, K-blocked layout), one prep pass fills all
    unsigned short* WT = (unsigned short*)alloc((size_t)1774592 * 8 * 2);  // 28.4 MB
    unsigned short* WT_up2 = WT;
    unsigned short* WT_up1 = WT + (size_t)55296 * 8;
    unsigned short* WT_up0 = WT + (size_t)221184 * 8;
    unsigned short* WT_s0  = WT + (size_t)414720 * 8;
    unsigned short* WT_s1  = WT + (size_t)857088 * 8;
    unsigned short* WT_s2  = WT + (size_t)1741824 * 8;
    // activations bf16
    unsigned short* xb3 = (unsigned short*)alloc((size_t)2000 * 128 * 2);
    unsigned short* xc2 = (unsigned short*)alloc((size_t)5000 * 192 * 2);
    unsigned short* xc1 = (unsigned short*)alloc((size_t)12000 * 224 * 2);
    unsigned short* xc0 = (unsigned short*)alloc((size_t)30000 * 256 * 2);
    unsigned short* ys  = (unsigned short*)alloc((size_t)30000 * 512 * 2);  // s0 out, then s1 out
    unsigned short* outb = (unsigned short*)alloc((size_t)30000 * 512 * 2); // bf16 conv result
    // per-layer cnt (contiguous, one memset) + stats right after
    int* cnt_all = (int*)alloc((size_t)107000 * 4);          // up2|up1|up0|s0|s1
    float* stats = (float*)alloc((size_t)6 * 1024 * 4);
    int* ell_all = (int*)alloc((size_t)107000 * ELL_CAP * 4); // 20.5 MB
    int* cnt_up2 = cnt_all;          int* ell_up2 = ell_all;
    int* cnt_up1 = cnt_all + 5000;   int* ell_up1 = ell_all + (size_t)5000 * ELL_CAP;
    int* cnt_up0 = cnt_all + 17000;  int* ell_up0 = ell_all + (size_t)17000 * ELL_CAP;
    int* cnt_s0  = cnt_all + 47000;  int* ell_s0  = ell_all + (size_t)47000 * ELL_CAP;
    int* cnt_s1  = cnt_all + 77000;  int* ell_s1  = ell_all + (size_t)77000 * ELL_CAP;
    // c partials: everything that's left
    size_t used = (size_t)(ws - (char*)d_ws);
    size_t cBudget = (ws_size > used + (1u << 20)) ? (ws_size - used - (1u << 20)) : 0;
    unsigned short* c = (unsigned short*)ws;

    // one memset covers cnt_all (428032 padded) + stats (24576)
    hipMemsetAsync(cnt_all, 0, 428032 + 24576, stream);
    // one prep dispatch: 6 transposes + 4 casts + 5 ell builds
    prep_all<<<18188, 256, 0, stream>>>(W_up2, W_up1, W_up0, W_s0, W_s1, W_s2,
                                        f0, f1, f2, f3,
                                        up2_out, up1_out, up0_out, sm0_out, sm1_out,
                                        WT, xb3, xc2, xc1, xc0, cnt_all, ell_all);

    // TN=256 sparse layer driver (nb chunks cover CoutPad; k chunked by budget)
    auto conv256 = [&](const unsigned short* Ain, const int* in_idx, const int* cnt,
                       const int* ell, const unsigned short* WTl,
                       int M, int Kp, int CoutPad, int Cout, int Nout, float* statsL) {
        size_t perK = (size_t)M * 256 * 2;
        int CK = (int)(cBudget / perK);
        if (CK < 1) CK = 1;
        if (CK > 27) CK = 27;
        for (int nb = 0; nb < CoutPad; nb += 256) {
            for (int k0 = 0; k0 < 27; k0 += CK) {
                int ck = (27 - k0 < CK) ? (27 - k0) : CK;
                spconv_gemm<256, false><<<dim3(div_up(M, 128), 1, ck), 256, 0, stream>>>(
                    Ain, WTl, in_idx, c, nullptr, M, Kp, CoutPad, nb, k0);
                reduce_ell<256><<<div_up(Nout, 8), 256, 0, stream>>>(
                    c, cnt, ell, outb, nb, Cout, Nout, k0 * M, (k0 + ck) * M, k0 > 0 ? 1 : 0);
            }
        }
        bn_stats_bf16<<<div_up(Nout, 64), 256, 0, stream>>>(outb, statsL, Nout, Cout, 64);
    };

    // ---- up2 (TN=128): xb3[2000,128] -> [5000,128]; concat f2 -> xc2[5000,192] ----
    spconv_gemm<128, false><<<dim3(13, 1, 27), 256, 0, stream>>>(xb3, WT_up2, up2_in, c, nullptr, 1600, 128, 128, 0, 0);
    reduce_ell<128><<<div_up(5000, 16), 256, 0, stream>>>(c, cnt_up2, ell_up2, outb, 0, 128, 5000, 0, 27 * 1600, 0);
    bn_stats_bf16<<<div_up(5000, 64), 256, 0, stream>>>(outb, stats + 0 * 1024, 5000, 128, 64);
    bn_apply_bb<<<div_up(5000 * 16, 256), 256, 0, stream>>>(outb, stats + 0 * 1024, g_up2, b_up2, xc2, 5000, 128, 192, 1.f / 5000);

    // ---- up1: xc2[5000,192] -> [12000,192]; concat f1 -> xc1[12000,224] ----
    conv256(xc2, up1_in, cnt_up1, ell_up1, WT_up1, 4000, 192, 256, 192, 12000, stats + 1 * 1024);
    bn_apply_bb<<<div_up(12000 * 24, 256), 256, 0, stream>>>(outb, stats + 1 * 1024, g_up1, b_up1, xc1, 12000, 192, 224, 1.f / 12000);

    // ---- up0: xc1[12000,224] -> [30000,224]; concat f0+pad -> xc0[30000,256] ----
    conv256(xc1, up0_in, cnt_up0, ell_up0, WT_up0, 10000, 224, 256, 224, 30000, stats + 2 * 1024);
    bn_apply_bb<<<div_up(30000 * 28, 256), 256, 0, stream>>>(outb, stats + 2 * 1024, g_up0, b_up0, xc0, 30000, 224, 256, 1.f / 30000);

    // ---- s0: xc0[30000,256] -> [30000,512] -> ys ----
    conv256(xc0, sm0_in, cnt_s0, ell_s0, WT_s0, 10000, 256, 512, 512, 30000, stats + 3 * 1024);
    bn_apply_bb<<<div_up(30000 * 64, 256), 256, 0, stream>>>(outb, stats + 3 * 1024, g_s0, b_s0, ys, 30000, 512, 512, 1.f / 30000);

    // ---- s1: ys[30000,512] -> [30000,512] -> ys ----
    conv256(ys, sm1_in, cnt_s1, ell_s1, WT_s1, 10000, 512, 512, 512, 30000, stats + 4 * 1024);
    bn_apply_bb<<<div_up(30000 * 64, 256), 256, 0, stream>>>(outb, stats + 4 * 1024, g_s1, b_s1, ys, 30000, 512, 512, 1.f / 30000);

    // ---- s2: dense ys[30000,512] @ W -> d_out, BN+ReLU in place ----
    float* out_f = (float*)d_out;
    spconv_gemm<256, true><<<dim3(235, 2, 1), 256, 0, stream>>>(ys, WT_s2, nullptr, nullptr, out_f, 30000, 512, 512, 0, 0);
    bn_stats<<<div_up(30000, 64), 256, 0, stream>>>(out_f, stats + 5 * 1024, 30000, 512, 64);
    bn_apply_f32<<<div_up(30000 * 128, 256), 256, 0, stream>>>(out_f, stats + 5 * 1024, g_s2, b_s2, 30000, 512, 1.f / 30000);
}

// Round 11
// 1091.305 us; speedup vs baseline: 1.1707x; 1.1707x over previous
//
#include <hip/hip_runtime.h>

typedef short bf16x8 __attribute__((ext_vector_type(8)));
typedef float f32x4 __attribute__((ext_vector_type(4)));

#define BN_EPS 1e-5f
#define ELL_CAP 48

__device__ __forceinline__ unsigned short f2b(float x) {
    union { float f; unsigned u; } v; v.f = x;
    unsigned r = v.u + 0x7FFFu + ((v.u >> 16) & 1u);
    return (unsigned short)(r >> 16);
}
__device__ __forceinline__ float b2f(unsigned short h) {
    union { unsigned u; float f; } v; v.u = ((unsigned)h) << 16;
    return v.f;
}
__device__ __forceinline__ void atomAddF(float* p, float v) { unsafeAtomicAdd(p, v); }

__device__ __forceinline__ void gload16(const void* g, void* l) {
    __builtin_amdgcn_global_load_lds((const __attribute__((address_space(1))) void*)g,
                                     (__attribute__((address_space(3))) void*)l, 16, 0, 0);
}

// ---- W[k][ci][co] f32 -> WT2 K-blocked bf16 layout:
//      chunk index ((k*KB + ci/32)*4 + (ci%32)/8) * CoutPad + co  holds 8 ci values.
//      Each K-step's B tile is contiguous in seg-major (LDS) order -> coalesced staging. ----
__global__ void transpose_cast_w2(const float* __restrict__ W, unsigned short* __restrict__ WT,
                                  int Cin, int Cout, int CinPad, int CoutPad, int total) {
    int i = blockIdx.x * blockDim.x + threadIdx.x;
    if (i >= total) return;
    int CB = CinPad >> 3;               // ci-blocks of 8
    int per_k = CB * CoutPad;
    int k = i / per_k, r = i - k * per_k;
    int cb = r / CoutPad, co = r - cb * CoutPad;
    const float* Wk = W + (size_t)k * Cin * Cout;
    bf16x8 ov;
    #pragma unroll
    for (int j = 0; j < 8; j++) {
        int ci = cb * 8 + j;
        float v = (ci < Cin && co < Cout) ? Wk[(size_t)ci * Cout + co] : 0.f;
        ov[j] = (short)f2b(v);
    }
    *(bf16x8*)(WT + (size_t)i * 8) = ov;   // i enumerates output chunks in order
}

// ---- cast fp32 [N,Csrc] -> bf16 dst[n*stride + off + j], zero-fill j>=Csrc ----
__global__ void cast_cols(const float* __restrict__ src, unsigned short* __restrict__ dst,
                          int N, int Csrc, int stride, int off, int wid) {
    int i = blockIdx.x * blockDim.x + threadIdx.x;
    if (i >= N * wid) return;
    int n = i / wid, j = i % wid;
    float v = (j < Csrc) ? src[(size_t)n * Csrc + j] : 0.f;
    dst[(size_t)n * stride + off + j] = f2b(v);
}

// ---- BN stats over bf16 activations ----
__global__ void bn_stats_bf16(const unsigned short* __restrict__ x, float* __restrict__ stats,
                              int N, int C, int rowsPerBlock) {
    int r0 = blockIdx.x * rowsPerBlock;
    int r1 = min(N, r0 + rowsPerBlock);
    for (int c = threadIdx.x; c < C; c += blockDim.x) {
        float s = 0.f, s2 = 0.f;
        for (int r = r0; r < r1; r++) {
            float v = b2f(x[(size_t)r * C + c]);
            s += v; s2 += v * v;
        }
        atomAddF(&stats[c], s);
        atomAddF(&stats[C + c], s2);
    }
}

// ---- BN stats over fp32 (dense s2 output) ----
__global__ void bn_stats(const float* __restrict__ x, float* __restrict__ stats,
                         int N, int C, int rowsPerBlock) {
    int r0 = blockIdx.x * rowsPerBlock;
    int r1 = min(N, r0 + rowsPerBlock);
    for (int c = threadIdx.x; c < C; c += blockDim.x) {
        float s = 0.f, s2 = 0.f;
        for (int r = r0; r < r1; r++) {
            float v = x[(size_t)r * C + c];
            s += v; s2 += v * v;
        }
        atomAddF(&stats[c], s);
        atomAddF(&stats[C + c], s2);
    }
}

// ---- BN apply + ReLU: bf16 src [N,C] -> bf16 dst (strided, for concat), x8 ----
__global__ void bn_apply_bb(const unsigned short* __restrict__ x, const float* __restrict__ stats,
                            const float* __restrict__ g, const float* __restrict__ b,
                            unsigned short* __restrict__ dst, int N, int C, int stride, float invN) {
    int i = blockIdx.x * blockDim.x + threadIdx.x;
    int C8 = C >> 3;
    if (i >= N * C8) return;
    int n = i / C8, cb = (i - n * C8) << 3;
    bf16x8 xv = *(const bf16x8*)(x + (size_t)n * C + cb);
    bf16x8 ov;
    #pragma unroll
    for (int j = 0; j < 8; j++) {
        int cc = cb + j;
        float mean = stats[cc] * invN;
        float var = stats[C + cc] * invN - mean * mean;
        float scale = g[cc] * rsqrtf(var + BN_EPS);
        float shift = b[cc] - mean * scale;
        ov[j] = (short)f2b(fmaxf(0.f, b2f((unsigned short)xv[j]) * scale + shift));
    }
    *(bf16x8*)(dst + (size_t)n * stride + cb) = ov;
}

// ---- BN apply + ReLU in-place fp32 (final output), x4 ----
__global__ void bn_apply_f32(float* __restrict__ x, const float* __restrict__ stats,
                             const float* __restrict__ g, const float* __restrict__ b,
                             int N, int C, float invN) {
    int i = blockIdx.x * blockDim.x + threadIdx.x;
    int C4 = C >> 2;
    if (i >= N * C4) return;
    int n = i / C4, cb = (i - n * C4) << 2;
    float* p = x + (size_t)n * C + cb;
    float4 xv = *(const float4*)p;
    float vs[4] = {xv.x, xv.y, xv.z, xv.w};
    #pragma unroll
    for (int j = 0; j < 4; j++) {
        int cc = cb + j;
        float mean = stats[cc] * invN;
        float var = stats[C + cc] * invN - mean * mean;
        float scale = g[cc] * rsqrtf(var + BN_EPS);
        float shift = b[cc] - mean * scale;
        vs[j] = fmaxf(0.f, vs[j] * scale + shift);
    }
    float4 ov = {vs[0], vs[1], vs[2], vs[3]};
    *(float4*)p = ov;
}

// ---- inverse-index (ELL) build: entry e = k*M+m ----
__global__ void ell_build(const int* __restrict__ out_idx, int total,
                          int* __restrict__ cnt, int* __restrict__ ell) {
    int e = blockIdx.x * blockDim.x + threadIdx.x;
    if (e >= total) return;
    int o = out_idx[e];
    int pos = atomicAdd(&cnt[o], 1);
    if (pos < ELL_CAP) ell[(size_t)o * ELL_CAP + pos] = e;
}

// ---- Phase B: sum bf16 partial rows per output row (CW-col chunk), write bf16.
//      PLAIN (cached) loads: partials were just written by the gemm and fit in
//      L3 — NT hints forced an HBM round-trip (R11 change). Pre-scan skips
//      untouched rows on accum passes; 4-deep loads in flight. ----
template<int CW>
__global__ __launch_bounds__(256)
void reduce_ell(const unsigned short* __restrict__ c, const int* __restrict__ cnt,
                const int* __restrict__ ell, unsigned short* __restrict__ outb,
                int nb, int Cout, int Nout, int k0row, int k1row, int accum) {
    constexpr int LPR = CW / 8;        // lanes per row
    constexpr int RPB = 256 / LPR;     // rows per block
    int tid = threadIdx.x;
    int o = blockIdx.x * RPB + tid / LPR;
    if (o >= Nout) return;
    int colL = (tid % LPR) * 8;
    int n = min(cnt[o], ELL_CAP);
    const int* er = ell + (size_t)o * ELL_CAP;

    // cheap pre-scan: any entry in this k-chunk?
    int nin = 0;
    for (int i = 0; i < n; i++) {
        int e = er[i];
        nin += (e >= k0row && e < k1row) ? 1 : 0;
    }
    if (accum && nin == 0) return;     // untouched row: skip RMW entirely

    float a[8] = {0.f, 0.f, 0.f, 0.f, 0.f, 0.f, 0.f, 0.f};
    if (nin > 0) {
        int i = 0;
        for (; i + 3 < n; i += 4) {    // 4 independent partial-row loads in flight
            int e0 = er[i], e1 = er[i + 1], e2 = er[i + 2], e3 = er[i + 3];
            float m0 = (e0 >= k0row && e0 < k1row) ? 1.f : 0.f;
            float m1 = (e1 >= k0row && e1 < k1row) ? 1.f : 0.f;
            float m2 = (e2 >= k0row && e2 < k1row) ? 1.f : 0.f;
            float m3 = (e3 >= k0row && e3 < k1row) ? 1.f : 0.f;
            size_t r0 = (m0 != 0.f) ? (size_t)(e0 - k0row) : 0;
            size_t r1 = (m1 != 0.f) ? (size_t)(e1 - k0row) : 0;
            size_t r2 = (m2 != 0.f) ? (size_t)(e2 - k0row) : 0;
            size_t r3 = (m3 != 0.f) ? (size_t)(e3 - k0row) : 0;
            bf16x8 u0 = *(const bf16x8*)(c + r0 * CW + colL);
            bf16x8 u1 = *(const bf16x8*)(c + r1 * CW + colL);
            bf16x8 u2 = *(const bf16x8*)(c + r2 * CW + colL);
            bf16x8 u3 = *(const bf16x8*)(c + r3 * CW + colL);
            #pragma unroll
            for (int j = 0; j < 8; j++)
                a[j] += (m0 * b2f((unsigned short)u0[j]) + m1 * b2f((unsigned short)u1[j]))
                      + (m2 * b2f((unsigned short)u2[j]) + m3 * b2f((unsigned short)u3[j]));
        }
        for (; i < n; i++) {
            int e0 = er[i];
            float m0 = (e0 >= k0row && e0 < k1row) ? 1.f : 0.f;
            size_t r0 = (m0 != 0.f) ? (size_t)(e0 - k0row) : 0;
            bf16x8 u0 = *(const bf16x8*)(c + r0 * CW + colL);
            #pragma unroll
            for (int j = 0; j < 8; j++) a[j] += m0 * b2f((unsigned short)u0[j]);
        }
    }
    int gc = nb + colL;
    if (gc < Cout) {   // Cout % 8 == 0 so whole 8-group is in-range
        unsigned short* op = outb + (size_t)o * Cout + gc;
        if (accum) {
            bf16x8 prev = *(const bf16x8*)op;
            #pragma unroll
            for (int j = 0; j < 8; j++) a[j] += b2f((unsigned short)prev[j]);
        }
        bf16x8 w;
        #pragma unroll
        for (int j = 0; j < 8; j++) w[j] = (short)f2b(a[j]);
        *(bf16x8*)op = w;
    }
}

// ---- Phase A: per-k gather GEMM, 128xTN tile, BK=32, fully async staging.
//      (R8/R9 config.) A: direct global_load_lds gather, source-chunk XOR
//      pre-swizzle (m173), linear [128][32] LDS dest, read slot = seg^(laneM&3).
//      B: K-blocked WT2, lane-contiguous global_load_lds. Both prefetch dist 2,
//      3 slots, uniform counted vmcnt + raw s_barrier.
//      R11: cpart stores are PLAIN (cached) — partials fit in L3 and are
//      consumed by the very next dispatch; NT forced an HBM round-trip.
//      LDS 72KB x 2 blocks/CU; register-limited at TN=256 (R4: 3 blocks spills). ----
template<int TN, bool DENSE>
__global__ __launch_bounds__(256, 2)
void spconv_gemm(const unsigned short* __restrict__ A, const unsigned short* __restrict__ BT,
                 const int* __restrict__ in_idx, unsigned short* __restrict__ cpart,
                 float* __restrict__ outf, int M, int Kp, int CoutPad, int nbase, int kbase) {
    constexpr int WN = TN / 32;        // B frags per wave
    constexpr int NBQ = (TN * 4) / 256; // B staging instrs per thread per k-step
    constexpr int BUFA = 128 * 32;     // shorts per A slot (8KB), linear [128][32]
    constexpr int BUFB = TN * 32;      // shorts per B slot
    constexpr int VW = NBQ + 2;        // steady top-of-loop vmcnt (batch t+1 in flight)
    __shared__ __align__(16) unsigned short As[3 * BUFA];
    __shared__ __align__(16) unsigned short Bs[3 * BUFB];
    int tid = threadIdx.x, wave = tid >> 6, lane = tid & 63;
    int wr = wave >> 1, wc = wave & 1;
    int m0 = blockIdx.x * 128;
    int n0 = nbase + blockIdx.y * TN;
    int kzl = blockIdx.z, kz = kbase + kzl;

    // A gather: lane covers (row_local rl, dest slot) ; source chunk = slot ^ (rl&3)
    int rl = lane >> 2, slot = lane & 3;
    int chunk = slot ^ (rl & 3);
    int ra0 = wave * 32 + rl, ra1 = ra0 + 16;   // (ra&3) == (rl&3)
    size_t arow0, arow1;
    if constexpr (DENSE) {
        arow0 = (size_t)min(m0 + ra0, M - 1);
        arow1 = (size_t)min(m0 + ra1, M - 1);
    } else {
        const int* idxk = in_idx + (size_t)kz * M;
        arow0 = (m0 + ra0 < M) ? (size_t)idxk[m0 + ra0] : 0;
        arow1 = (m0 + ra1 < M) ? (size_t)idxk[m0 + ra1] : 0;
    }
    const unsigned short* gA0 = A + arow0 * Kp + chunk * 8;
    const unsigned short* gA1 = A + arow1 * Kp + chunk * 8;
    // wave-uniform LDS dests (lane offset is implicit lane*16B):
    unsigned short* lA0 = As + (size_t)(wave * 32) * 32;        // rows wave*32..+15
    unsigned short* lA1 = As + (size_t)(wave * 32 + 16) * 32;   // rows +16..+31

    // WT2: chunk ((k*KB + kb)*4 + seg)*CoutPad + co
    const unsigned short* BTk = BT + (size_t)kz * CoutPad * Kp;
    const unsigned short* gB[NBQ];
    unsigned short* lB[NBQ];
    #pragma unroll
    for (int q = 0; q < NBQ; q++) {
        int c0 = q * 256 + wave * 64;           // chunk id within the tile
        int seg0 = c0 / TN, col0 = c0 % TN;
        gB[q] = BTk + ((size_t)seg0 * CoutPad + (size_t)(n0 + col0 + lane)) * 8;
        lB[q] = Bs + (size_t)c0 * 8;            // slot-relative; add slot*BUFB
    }
    const size_t bstep = (size_t)CoutPad * 32;   // shorts per k-iter (kb+1)

    f32x4 acc[4][WN];
    #pragma unroll
    for (int i = 0; i < 4; i++)
        #pragma unroll
        for (int j = 0; j < WN; j++) acc[i][j] = (f32x4)(0.f);

    int laneM = lane & 15, seg = lane >> 4;
    // read: row (wr*64 + i*16 + laneM); chunk seg lives at slot seg^(row&3)=seg^(laneM&3)
    int aoff = (wr * 64 + laneM) * 32 + ((seg ^ (laneM & 3)) << 3);
    int boff = (seg * TN + wc * (TN / 2) + laneM) * 8;

    int nIter = Kp >> 5;

    // batch issue: A(2) + B(NBQ) gloads for k-step s into slot s%3
    auto stage = [&](int s) {
        int sa = (s % 3) * BUFA, sb = (s % 3) * BUFB;
        gload16(gA0 + s * 32, lA0 + sa);
        gload16(gA1 + s * 32, lA1 + sa);
        #pragma unroll
        for (int q = 0; q < NBQ; q++) gload16(gB[q] + (size_t)s * bstep, lB[q] + sb);
    };

    // prologue: batch(0), batch(1)
    stage(0);
    if (nIter > 1) stage(1); else stage(0);   // keep queue depth uniform

    for (int t = 0; t < nIter; t++) {
        // drain batch(t), leave batch(t+1)'s VW loads in flight across the barrier
        asm volatile("s_waitcnt vmcnt(%0)" :: "n"(VW) : "memory");
        __builtin_amdgcn_s_barrier();
        __builtin_amdgcn_sched_barrier(0);

        const unsigned short* ab = As + (t % 3) * BUFA + aoff;
        const unsigned short* bb = Bs + (t % 3) * BUFB + boff;
        bf16x8 af[4], bfr[WN];
        #pragma unroll
        for (int i = 0; i < 4; i++) af[i] = *(const bf16x8*)(ab + i * 512);
        #pragma unroll
        for (int j = 0; j < WN; j++) bfr[j] = *(const bf16x8*)(bb + j * 128);

        // batch(t+2), clamped to keep the VMEM queue depth constant; the dup
        // targets slot (t+2)%3 which is never the slot read this or next body.
        int tn = (t + 2 < nIter) ? (t + 2) : (nIter - 1);
        {
            int sa = ((t + 2) % 3) * BUFA, sb = ((t + 2) % 3) * BUFB;
            gload16(gA0 + tn * 32, lA0 + sa);
            gload16(gA1 + tn * 32, lA1 + sa);
            #pragma unroll
            for (int q = 0; q < NBQ; q++) gload16(gB[q] + (size_t)tn * bstep, lB[q] + sb);
        }

        #pragma unroll
        for (int i = 0; i < 4; i++)
            #pragma unroll
            for (int j = 0; j < WN; j++)
                acc[i][j] = __builtin_amdgcn_mfma_f32_16x16x32_bf16(af[i], bfr[j], acc[i][j], 0, 0, 0);
    }

    // C/D layout: col=lane&15, row=(lane>>4)*4+r  [m89/m91 verified]
    int rbase = seg * 4;
    #pragma unroll
    for (int i = 0; i < 4; i++) {
        #pragma unroll
        for (int r = 0; r < 4; r++) {
            int gm = m0 + wr * 64 + i * 16 + rbase + r;
            if (gm < M) {
                #pragma unroll
                for (int j = 0; j < WN; j++) {
                    int colL = wc * (TN / 2) + j * 16 + laneM;
                    if constexpr (DENSE) {
                        outf[(size_t)gm * CoutPad + n0 + colL] = acc[i][j][r];
                    } else {
                        cpart[((size_t)kzl * M + gm) * TN + colL] =
                            (unsigned short)f2b(acc[i][j][r]);
                    }
                }
            }
        }
    }
}

static inline int div_up(int a, int b) { return (a + b - 1) / b; }

extern "C" void kernel_launch(void* const* d_in, const int* in_sizes, int n_in,
                              void* d_out, int out_size, void* d_ws, size_t ws_size,
                              hipStream_t stream) {
    const float* f0 = (const float*)d_in[0];
    const float* f1 = (const float*)d_in[1];
    const float* f2 = (const float*)d_in[2];
    const float* f3 = (const float*)d_in[3];
    const float* W_up2 = (const float*)d_in[4];
    const float* W_up1 = (const float*)d_in[5];
    const float* W_up0 = (const float*)d_in[6];
    const float* W_s0  = (const float*)d_in[7];
    const float* W_s1  = (const float*)d_in[8];
    const float* W_s2  = (const float*)d_in[9];
    const float* g_up2 = (const float*)d_in[10]; const float* b_up2 = (const float*)d_in[11];
    const float* g_up1 = (const float*)d_in[12]; const float* b_up1 = (const float*)d_in[13];
    const float* g_up0 = (const float*)d_in[14]; const float* b_up0 = (const float*)d_in[15];
    const float* g_s0  = (const float*)d_in[16]; const float* b_s0  = (const float*)d_in[17];
    const float* g_s1  = (const float*)d_in[18]; const float* b_s1  = (const float*)d_in[19];
    const float* g_s2  = (const float*)d_in[20]; const float* b_s2  = (const float*)d_in[21];
    const int* up2_in  = (const int*)d_in[22]; const int* up2_out = (const int*)d_in[23];
    const int* up1_in  = (const int*)d_in[24]; const int* up1_out = (const int*)d_in[25];
    const int* up0_in  = (const int*)d_in[26]; const int* up0_out = (const int*)d_in[27];
    const int* sm0_in  = (const int*)d_in[28]; const int* sm0_out = (const int*)d_in[29];
    const int* sm1_in  = (const int*)d_in[30]; const int* sm1_out = (const int*)d_in[31];

    char* ws = (char*)d_ws;
    auto alloc = [&](size_t bytes) { char* p = ws; ws += (bytes + 255) & ~(size_t)255; return p; };

    // shared weight buffer (K-blocked layout; rebuilt per layer right before use)
    unsigned short* WT = (unsigned short*)alloc((size_t)27 * 512 * 512 * 2);  // 14.2 MB max (s1)
    // activations bf16
    unsigned short* xb3 = (unsigned short*)alloc((size_t)2000 * 128 * 2);
    unsigned short* xc2 = (unsigned short*)alloc((size_t)5000 * 192 * 2);
    unsigned short* xc1 = (unsigned short*)alloc((size_t)12000 * 224 * 2);
    unsigned short* xc0 = (unsigned short*)alloc((size_t)30000 * 256 * 2);
    unsigned short* ys  = (unsigned short*)alloc((size_t)30000 * 512 * 2);  // s0 out, then s1 out
    unsigned short* outb = (unsigned short*)alloc((size_t)30000 * 512 * 2); // bf16 conv result
    int* cnt = (int*)alloc((size_t)30000 * 4);
    int* ell = (int*)alloc((size_t)30000 * ELL_CAP * 4);
    float* stats = (float*)alloc((size_t)6 * 1024 * 4);
    // c partials: everything that's left
    size_t used = (size_t)(ws - (char*)d_ws);
    size_t cBudget = (ws_size > used + (1u << 20)) ? (ws_size - used - (1u << 20)) : 0;
    unsigned short* c = (unsigned short*)ws;

    hipMemsetAsync(stats, 0, (size_t)6 * 1024 * 4, stream);
    cast_cols<<<div_up(2000 * 128, 256), 256, 0, stream>>>(f3, xb3, 2000, 128, 128, 0, 128);

    // TN=256 sparse layer driver (single n-chunk covers CoutPad<=256; else 2 chunks)
    auto conv256 = [&](const unsigned short* Ain, const int* in_idx, const int* out_idx,
                       int M, int Kp, int CoutPad, int Cout, int Nout, float* statsL) {
        hipMemsetAsync(cnt, 0, (size_t)Nout * 4, stream);
        ell_build<<<div_up(27 * M, 256), 256, 0, stream>>>(out_idx, 27 * M, cnt, ell);
        size_t perK = (size_t)M * 256 * 2;
        int CK = (int)(cBudget / perK);
        if (CK < 1) CK = 1;
        if (CK > 27) CK = 27;
        for (int nb = 0; nb < CoutPad; nb += 256) {
            for (int k0 = 0; k0 < 27; k0 += CK) {
                int ck = (27 - k0 < CK) ? (27 - k0) : CK;
                spconv_gemm<256, false><<<dim3(div_up(M, 128), 1, ck), 256, 0, stream>>>(
                    Ain, WT, in_idx, c, nullptr, M, Kp, CoutPad, nb, k0);
                reduce_ell<256><<<div_up(Nout, 8), 256, 0, stream>>>(
                    c, cnt, ell, outb, nb, Cout, Nout, k0 * M, (k0 + ck) * M, k0 > 0 ? 1 : 0);
            }
        }
        bn_stats_bf16<<<div_up(Nout, 64), 256, 0, stream>>>(outb, statsL, Nout, Cout, 64);
    };

    // ---- up2 (TN=128): xb3[2000,128] -> [5000,128]; concat f2 -> xc2[5000,192] ----
    {
        int total = 27 * (128 >> 3) * 128;
        transpose_cast_w2<<<div_up(total, 256), 256, 0, stream>>>(W_up2, WT, 128, 128, 128, 128, total);
    }
    hipMemsetAsync(cnt, 0, (size_t)5000 * 4, stream);
    ell_build<<<div_up(27 * 1600, 256), 256, 0, stream>>>(up2_out, 27 * 1600, cnt, ell);
    spconv_gemm<128, false><<<dim3(13, 1, 27), 256, 0, stream>>>(xb3, WT, up2_in, c, nullptr, 1600, 128, 128, 0, 0);
    reduce_ell<128><<<div_up(5000, 16), 256, 0, stream>>>(c, cnt, ell, outb, 0, 128, 5000, 0, 27 * 1600, 0);
    bn_stats_bf16<<<div_up(5000, 64), 256, 0, stream>>>(outb, stats + 0 * 1024, 5000, 128, 64);
    bn_apply_bb<<<div_up(5000 * 16, 256), 256, 0, stream>>>(outb, stats + 0 * 1024, g_up2, b_up2, xc2, 5000, 128, 192, 1.f / 5000);
    cast_cols<<<div_up(5000 * 64, 256), 256, 0, stream>>>(f2, xc2, 5000, 64, 192, 128, 64);

    // ---- up1: xc2[5000,192] -> [12000,192]; concat f1 -> xc1[12000,224] ----
    {
        int total = 27 * (192 >> 3) * 256;
        transpose_cast_w2<<<div_up(total, 256), 256, 0, stream>>>(W_up1, WT, 192, 192, 192, 256, total);
    }
    conv256(xc2, up1_in, up1_out, 4000, 192, 256, 192, 12000, stats + 1 * 1024);
    bn_apply_bb<<<div_up(12000 * 24, 256), 256, 0, stream>>>(outb, stats + 1 * 1024, g_up1, b_up1, xc1, 12000, 192, 224, 1.f / 12000);
    cast_cols<<<div_up(12000 * 32, 256), 256, 0, stream>>>(f1, xc1, 12000, 32, 224, 192, 32);

    // ---- up0: xc1[12000,224] -> [30000,224]; concat f0+pad -> xc0[30000,256] ----
    {
        int total = 27 * (224 >> 3) * 256;
        transpose_cast_w2<<<div_up(total, 256), 256, 0, stream>>>(W_up0, WT, 224, 224, 224, 256, total);
    }
    conv256(xc1, up0_in, up0_out, 10000, 224, 256, 224, 30000, stats + 2 * 1024);
    bn_apply_bb<<<div_up(30000 * 28, 256), 256, 0, stream>>>(outb, stats + 2 * 1024, g_up0, b_up0, xc0, 30000, 224, 256, 1.f / 30000);
    cast_cols<<<div_up(30000 * 32, 256), 256, 0, stream>>>(f0, xc0, 30000, 16, 256, 224, 32); // 16 real + 16 pad

    // ---- s0: xc0[30000,256] -> [30000,512] -> ys ----
    {
        int total = 27 * (256 >> 3) * 512;
        transpose_cast_w2<<<div_up(total, 256), 256, 0, stream>>>(W_s0, WT, 240, 512, 256, 512, total);
    }
    conv256(xc0, sm0_in, sm0_out, 10000, 256, 512, 512, 30000, stats + 3 * 1024);
    bn_apply_bb<<<div_up(30000 * 64, 256), 256, 0, stream>>>(outb, stats + 3 * 1024, g_s0, b_s0, ys, 30000, 512, 512, 1.f / 30000);

    // ---- s1: ys[30000,512] -> [30000,512] -> ys ----
    {
        int total = 27 * (512 >> 3) * 512;
        transpose_cast_w2<<<div_up(total, 256), 256, 0, stream>>>(W_s1, WT, 512, 512, 512, 512, total);
    }
    conv256(ys, sm1_in, sm1_out, 10000, 512, 512, 512, 30000, stats + 4 * 1024);
    bn_apply_bb<<<div_up(30000 * 64, 256), 256, 0, stream>>>(outb, stats + 4 * 1024, g_s1, b_s1, ys, 30000, 512, 512, 1.f / 30000);

    // ---- s2: dense ys[30000,512] @ W -> d_out, BN+ReLU in place ----
    {
        int total = 1 * (512 >> 3) * 512;
        transpose_cast_w2<<<div_up(total, 256), 256, 0, stream>>>(W_s2, WT, 512, 512, 512, 512, total);
    }
    float* out_f = (float*)d_out;
    spconv_gemm<256, true><<<dim3(235, 2, 1), 256, 0, stream>>>(ys, WT, nullptr, nullptr, out_f, 30000, 512, 512, 0, 0);
    bn_stats<<<div_up(30000, 64), 256, 0, stream>>>(out_f, stats + 5 * 1024, 30000, 512, 64);
    bn_apply_f32<<<div_up(30000 * 128, 256), 256, 0, stream>>>(out_f, stats + 5 * 1024, g_s2, b_s2, 30000, 512, 1.f / 30000);
}